// Round 17
// baseline (121.432 us; speedup 1.0000x reference)
//
#include <hip/hip_runtime.h>
#include <math.h>

#define NN 50000          // nodes
#define NE 800000         // edges (without self loops)
#define NT (NE + NN)      // edges incl self loops
#define NBUCK 196         // dst>>8 buckets (256 nodes each)
#define BE 4096           // edges per bucket block
#define NBLK_B ((NT + BE - 1) / BE)              // 208
#define CAP 6144          // static staging capacity per bucket (max ~4.6k)
#define NBLK_G ((NN + 63) / 64)                  // 782 gemm1 blocks

typedef short bf16x8 __attribute__((ext_vector_type(8)));
typedef float f32x4 __attribute__((ext_vector_type(4)));
union U16x8 { uint4 u; bf16x8 s; };

__device__ __forceinline__ unsigned pk_bf16x2(float x, float y) {
  unsigned ux = __float_as_uint(x); ux = ux + 0x7FFFu + ((ux >> 16) & 1u);
  unsigned uy = __float_as_uint(y); uy = uy + 0x7FFFu + ((uy >> 16) & 1u);
  return (ux >> 16) | (uy & 0xFFFF0000u);
}
__device__ __forceinline__ unsigned short bf16_1(float x) {
  unsigned u = __float_as_uint(x); u = u + 0x7FFFu + ((u >> 16) & 1u);
  return (unsigned short)(u >> 16);
}
__device__ __forceinline__ float blo(unsigned v) { return __uint_as_float(v << 16); }
__device__ __forceinline__ float bhi(unsigned v) { return __uint_as_float(v & 0xFFFF0000u); }

// ================= prep: weight frags + static bucket cursors =================
__global__ __launch_bounds__(256) void k_prep(const float* __restrict__ W1, const float* __restrict__ W2,
                                              unsigned short* __restrict__ w1f,
                                              unsigned short* __restrict__ w2f,
                                              int* __restrict__ bcur) {
  int i = blockIdx.x * 256 + threadIdx.x;
  if (i < NBUCK) bcur[i] = i * CAP;
  if (i < 128 * 128) {
    int k = i >> 7, col = i & 127;
    int ct = col >> 4, kt = k >> 5, lane = (((k >> 3) & 3) << 4) | (col & 15), j = k & 7;
    w1f[(((ct << 2) | kt) * 64 + lane) * 8 + j] = bf16_1(W1[i]);
  } else if (i < 128 * 128 + 64 * 64) {
    int e = i - 128 * 128;
    int k = e >> 6, col = e & 63;
    int ct = col >> 4, kt = k >> 5, lane = (((k >> 3) & 3) << 4) | (col & 15), j = k & 7;
    w2f[(((ct << 1) | kt) * 64 + lane) * 8 + j] = bf16_1(W2[e]);
  }
}

// ================= fused hetero kernel: bucketF (blocks 0..NBLK_B) + gemm1 (rest) =================
__global__ __launch_bounds__(256) void k_gb(
    const int* __restrict__ src, const int* __restrict__ dst,
    int* __restrict__ bcur, unsigned* __restrict__ staging,
    const float* __restrict__ x, const unsigned short* __restrict__ w1f,
    const float* __restrict__ asw_g, const float* __restrict__ adw_g,
    unsigned short* __restrict__ h1b, float* __restrict__ as1, float* __restrict__ ad1) {
  __shared__ int hist[NBUCK];
  __shared__ int base[NBUCK];
  if (blockIdx.x < NBLK_B) {
    const int t = threadIdx.x;
    const int e0 = blockIdx.x * BE;
    if (t < NBUCK) hist[t] = 0;
    __syncthreads();
    for (int j = t; j < BE; j += 256) {
      int i = e0 + j;
      if (i >= NT) break;
      int d = (i < NE) ? dst[i] : (i - NE);
      atomicAdd(&hist[d >> 8], 1);
    }
    __syncthreads();
    if (t < NBUCK) {
      int c = hist[t];
      base[t] = c ? atomicAdd(&bcur[t], c) : 0;
      hist[t] = 0;
    }
    __syncthreads();
    for (int j = t; j < BE; j += 256) {
      int i = e0 + j;
      if (i >= NT) break;
      int s, d;
      if (i < NE) { s = src[i]; d = dst[i]; } else { s = d = i - NE; }
      int b = d >> 8;
      int off = atomicAdd(&hist[b], 1);
      staging[base[b] + off] = ((unsigned)d << 16) | (unsigned)s;
    }
    return;
  }
  // ---- gemm1 ----
  const int bid = blockIdx.x - NBLK_B;
  const int t = threadIdx.x;
  const int wid = t >> 6, l = t & 63;
  const int lr = l & 15, lg = l >> 4;
  const int arow = bid * 64 + wid * 16 + lr;
  const bool aok = arow < NN;

  float asw_t[8], adw_t[8];
#pragma unroll
  for (int ct = 0; ct < 8; ++ct) {
    asw_t[ct] = asw_g[ct * 16 + lr];
    adw_t[ct] = adw_g[ct * 16 + lr];
  }

  f32x4 acc[8];
#pragma unroll
  for (int ct = 0; ct < 8; ++ct) acc[ct] = (f32x4){0.f, 0.f, 0.f, 0.f};

#pragma unroll
  for (int kt = 0; kt < 4; ++kt) {
    U16x8 a;
    if (aok) {
      const float* xp = &x[(long long)arow * 128 + kt * 32 + lg * 8];
      float4 f0 = *(const float4*)xp;
      float4 f1 = *(const float4*)(xp + 4);
      a.u.x = pk_bf16x2(f0.x, f0.y); a.u.y = pk_bf16x2(f0.z, f0.w);
      a.u.z = pk_bf16x2(f1.x, f1.y); a.u.w = pk_bf16x2(f1.z, f1.w);
    } else {
      a.u = make_uint4(0, 0, 0, 0);
    }
#pragma unroll
    for (int ct = 0; ct < 8; ++ct) {
      U16x8 b;
      b.u = *(const uint4*)&w1f[(((ct << 2) | kt) * 64 + l) * 8];
      acc[ct] = __builtin_amdgcn_mfma_f32_16x16x32_bf16(a.s, b.s, acc[ct], 0, 0, 0);
    }
  }

  const int gr0 = bid * 64 + wid * 16 + lg * 4;
#pragma unroll
  for (int reg = 0; reg < 4; ++reg) {
    int grow = gr0 + reg;
    bool ok = grow < NN;
    float s0 = 0.f, s1 = 0.f, d0 = 0.f, d1 = 0.f;
#pragma unroll
    for (int ct = 0; ct < 8; ++ct) {
      float v = acc[ct][reg];
      if (ok) h1b[(long long)grow * 128 + ct * 16 + lr] = bf16_1(v);
      if (ct < 4) { s0 += v * asw_t[ct]; d0 += v * adw_t[ct]; }
      else        { s1 += v * asw_t[ct]; d1 += v * adw_t[ct]; }
    }
#pragma unroll
    for (int off = 1; off < 16; off <<= 1) {
      s0 += __shfl_xor(s0, off); d0 += __shfl_xor(d0, off);
      s1 += __shfl_xor(s1, off); d1 += __shfl_xor(d1, off);
    }
    if (ok && lr == 0) {
      as1[grow * 2] = s0; as1[grow * 2 + 1] = s1;
      ad1[grow * 2] = d0; ad1[grow * 2 + 1] = d1;
    }
  }
}

// ================= per-bucket: inline bucket-scan + build rowptr + scatter =================
__global__ __launch_bounds__(256) void k_scatter2(const unsigned* __restrict__ staging,
                                                  const int* __restrict__ bcur,
                                                  int* __restrict__ rowptr,
                                                  unsigned short* __restrict__ csr16) {
  __shared__ int lcnt[256];
  __shared__ int wsum[4];
  __shared__ int sOff, sTot;
  const int b = blockIdx.x;
  const int t = threadIdx.x;
  const int nlo = b << 8;
  const int l = t & 63, w = t >> 6;

  int bc = (t < NBUCK) ? bcur[t] - t * CAP : 0;
  int sc = bc;
#pragma unroll
  for (int off = 1; off < 64; off <<= 1) {
    int u = __shfl_up(sc, off);
    if (l >= off) sc += u;
  }
  if (l == 63) wsum[w] = sc;
  __syncthreads();
  {
    int wo = 0;
    for (int i = 0; i < w; ++i) wo += wsum[i];
    int incl = sc + wo;
    if (t == b) sOff = incl - bc;
    if (t == 255) sTot = incl;
  }
  lcnt[t] = 0;
  __syncthreads();

  const int s0 = b * CAP;
  const int cnt = bcur[b] - s0;
  for (int k = t; k < cnt; k += 256)
    atomicAdd(&lcnt[(int)(staging[s0 + k] >> 16) - nlo], 1);
  __syncthreads();
  int v = lcnt[t];
  int sc2 = v;
#pragma unroll
  for (int off = 1; off < 64; off <<= 1) {
    int u = __shfl_up(sc2, off);
    if (l >= off) sc2 += u;
  }
  __syncthreads();
  if (l == 63) wsum[w] = sc2;
  __syncthreads();
  int wo = 0;
  for (int i = 0; i < w; ++i) wo += wsum[i];
  const int base = sOff + sc2 + wo - v;
  if (nlo + t < NN) rowptr[nlo + t] = base;
  if (b == NBUCK - 1 && t == 0) rowptr[NN] = sTot;
  __syncthreads();
  lcnt[t] = base;
  __syncthreads();
  for (int k = t; k < cnt; k += 256) {
    unsigned e = staging[s0 + k];
    int d = (int)(e >> 16) - nlo;
    int pos = atomicAdd(&lcnt[d], 1);
    csr16[pos] = (unsigned short)(e & 0xFFFFu);
  }
}

// ================= layer 1 fused GAT + layer 2 GEMM (block = 8 nodes) =================
// half-wave per node; lane l (0..31) owns channels 4l..4l+3; head hd=l>>4.
// After aggregation, out1 rows go to LDS and wave 0 runs the 8-row MFMA vs W2.
__global__ __launch_bounds__(256) void k_gat1(
    const int* __restrict__ rowptr, const unsigned short* __restrict__ csr16,
    const uint2* __restrict__ h1x2, const float2* __restrict__ as1,
    const float2* __restrict__ ad1, const float* __restrict__ b1,
    const unsigned short* __restrict__ w2f,
    const float* __restrict__ as2w_g, const float* __restrict__ ad2w_g,
    unsigned short* __restrict__ h2b, float* __restrict__ as2, float* __restrict__ ad2) {
  __shared__ float4 sw[4][2][64];     // [wave][node-in-wave][slot] = {s_bits, w0, w1, -}
  __shared__ unsigned o1[8][32];      // out1 rows, bf16x2 (8 nodes x 64 ch)
  const int t = threadIdx.x;
  const int wv = t >> 6;
  const int p = t & 63;
  const int hw = p >> 5;
  const int l = p & 31;
  const int n = blockIdx.x * 8 + wv * 2 + hw;   // always < NN (6250*8 == NN)
  const int beg = rowptr[n], end = rowptr[n + 1];
  const int deg = end - beg;
  const float2 adn = ad1[n];
  const int hd = l >> 4;

  float a0 = 0.f, a1 = 0.f, a2 = 0.f, a3 = 0.f;
  float inv;

  if (deg <= 64) {
    int sA = 0, sB = 0;
    float e0A = -1e30f, e1A = -1e30f, e0B = -1e30f, e1B = -1e30f;
    if (l < deg) {
      sA = csr16[beg + l];
      float2 a = as1[sA];
      e0A = a.x + adn.x; e0A = fmaxf(e0A, 0.2f * e0A);
      e1A = a.y + adn.y; e1A = fmaxf(e1A, 0.2f * e1A);
    }
    if (l + 32 < deg) {
      sB = csr16[beg + l + 32];
      float2 a = as1[sB];
      e0B = a.x + adn.x; e0B = fmaxf(e0B, 0.2f * e0B);
      e1B = a.y + adn.y; e1B = fmaxf(e1B, 0.2f * e1B);
    }
    float m0 = fmaxf(e0A, e0B), m1 = fmaxf(e1A, e1B);
#pragma unroll
    for (int off = 1; off < 32; off <<= 1) {
      m0 = fmaxf(m0, __shfl_xor(m0, off));
      m1 = fmaxf(m1, __shfl_xor(m1, off));
    }
    float w0A = (l < deg) ? __expf(e0A - m0) : 0.f;
    float w1A = (l < deg) ? __expf(e1A - m1) : 0.f;
    float w0B = (l + 32 < deg) ? __expf(e0B - m0) : 0.f;
    float w1B = (l + 32 < deg) ? __expf(e1B - m1) : 0.f;
    float d0 = w0A + w0B, d1 = w1A + w1B;
#pragma unroll
    for (int off = 1; off < 32; off <<= 1) {
      d0 += __shfl_xor(d0, off);
      d1 += __shfl_xor(d1, off);
    }
    sw[wv][hw][l]      = make_float4(__int_as_float(sA), w0A, w1A, 0.f);
    sw[wv][hw][l + 32] = make_float4(__int_as_float(sB), w0B, w1B, 0.f);
    __builtin_amdgcn_wave_barrier();
    inv = 1.f / ((hd ? d1 : d0) + 1e-16f);

    int j = 0;
    for (; j + 8 <= deg; j += 8) {
      float4 a[8]; uint2 v[8];
#pragma unroll
      for (int u = 0; u < 8; ++u) a[u] = sw[wv][hw][j + u];
#pragma unroll
      for (int u = 0; u < 8; ++u) v[u] = h1x2[(__float_as_int(a[u].x) << 5) + l];
#pragma unroll
      for (int u = 0; u < 8; ++u) {
        float wgt = hd ? a[u].z : a[u].y;
        a0 += wgt * blo(v[u].x); a1 += wgt * bhi(v[u].x);
        a2 += wgt * blo(v[u].y); a3 += wgt * bhi(v[u].y);
      }
    }
    if (j + 4 <= deg) {
      float4 a[4]; uint2 v[4];
#pragma unroll
      for (int u = 0; u < 4; ++u) a[u] = sw[wv][hw][j + u];
#pragma unroll
      for (int u = 0; u < 4; ++u) v[u] = h1x2[(__float_as_int(a[u].x) << 5) + l];
#pragma unroll
      for (int u = 0; u < 4; ++u) {
        float wgt = hd ? a[u].z : a[u].y;
        a0 += wgt * blo(v[u].x); a1 += wgt * bhi(v[u].x);
        a2 += wgt * blo(v[u].y); a3 += wgt * bhi(v[u].y);
      }
      j += 4;
    }
    for (; j < deg; ++j) {
      float4 a = sw[wv][hw][j];
      uint2 v = h1x2[(__float_as_int(a.x) << 5) + l];
      float wgt = hd ? a.z : a.y;
      a0 += wgt * blo(v.x); a1 += wgt * bhi(v.x);
      a2 += wgt * blo(v.y); a3 += wgt * bhi(v.y);
    }
  } else {
    float m0 = -1e30f, d0 = 0.f, m1 = -1e30f, d1 = 0.f;
    for (int k = beg + l; k < end; k += 32) {
      float2 a = as1[csr16[k]];
      float e0 = a.x + adn.x; e0 = fmaxf(e0, 0.2f * e0);
      float e1 = a.y + adn.y; e1 = fmaxf(e1, 0.2f * e1);
      if (e0 > m0) { d0 *= __expf(m0 - e0); m0 = e0; }
      d0 += __expf(e0 - m0);
      if (e1 > m1) { d1 *= __expf(m1 - e1); m1 = e1; }
      d1 += __expf(e1 - m1);
    }
#pragma unroll
    for (int off = 1; off < 32; off <<= 1) {
      float mo = __shfl_xor(m0, off), dd = __shfl_xor(d0, off);
      float mn = fmaxf(m0, mo);
      d0 = d0 * __expf(m0 - mn) + dd * __expf(mo - mn);
      m0 = mn;
      mo = __shfl_xor(m1, off); dd = __shfl_xor(d1, off);
      mn = fmaxf(m1, mo);
      d1 = d1 * __expf(m1 - mn) + dd * __expf(mo - mn);
      m1 = mn;
    }
    inv = 1.f / ((hd ? d1 : d0) + 1e-16f);
    for (int c0 = beg; c0 < end; c0 += 64) {
      int nc = end - c0; if (nc > 64) nc = 64;
      int sA = 0, sB = 0; float w0A = 0.f, w1A = 0.f, w0B = 0.f, w1B = 0.f;
      if (l < nc) {
        sA = csr16[c0 + l];
        float2 a = as1[sA];
        float e0 = a.x + adn.x; e0 = fmaxf(e0, 0.2f * e0);
        float e1 = a.y + adn.y; e1 = fmaxf(e1, 0.2f * e1);
        w0A = __expf(e0 - m0); w1A = __expf(e1 - m1);
      }
      if (l + 32 < nc) {
        sB = csr16[c0 + l + 32];
        float2 a = as1[sB];
        float e0 = a.x + adn.x; e0 = fmaxf(e0, 0.2f * e0);
        float e1 = a.y + adn.y; e1 = fmaxf(e1, 0.2f * e1);
        w0B = __expf(e0 - m0); w1B = __expf(e1 - m1);
      }
      __builtin_amdgcn_wave_barrier();
      sw[wv][hw][l]      = make_float4(__int_as_float(sA), w0A, w1A, 0.f);
      sw[wv][hw][l + 32] = make_float4(__int_as_float(sB), w0B, w1B, 0.f);
      __builtin_amdgcn_wave_barrier();
      for (int j = 0; j < nc; ++j) {
        float4 a = sw[wv][hw][j];
        uint2 v = h1x2[(__float_as_int(a.x) << 5) + l];
        float wgt = hd ? a.z : a.y;
        a0 += wgt * blo(v.x); a1 += wgt * bhi(v.x);
        a2 += wgt * blo(v.y); a3 += wgt * bhi(v.y);
      }
      __builtin_amdgcn_wave_barrier();
    }
  }

  // normalize, head-mean via shfl_xor(16), ELU -> out1 row to LDS (bf16)
  a0 *= inv; a1 *= inv; a2 *= inv; a3 *= inv;
  float c0 = __shfl_xor(a0, 16), c1 = __shfl_xor(a1, 16),
        c2 = __shfl_xor(a2, 16), c3 = __shfl_xor(a3, 16);
  if (l < 16) {
    float u0 = 0.5f * (a0 + c0) + b1[4 * l + 0];
    float u1 = 0.5f * (a1 + c1) + b1[4 * l + 1];
    float u2 = 0.5f * (a2 + c2) + b1[4 * l + 2];
    float u3 = 0.5f * (a3 + c3) + b1[4 * l + 3];
    u0 = u0 > 0.f ? u0 : expm1f(u0);
    u1 = u1 > 0.f ? u1 : expm1f(u1);
    u2 = u2 > 0.f ? u2 : expm1f(u2);
    u3 = u3 > 0.f ? u3 : expm1f(u3);
    *(uint2*)&o1[wv * 2 + hw][2 * l] = make_uint2(pk_bf16x2(u0, u1), pk_bf16x2(u2, u3));
  }
  __syncthreads();

  // ---- fused layer-2 GEMM: wave 0 does an 8-row MFMA vs W2 ----
  if (t < 64) {
    const int lr = t & 15, lg = t >> 4;
    f32x4 acc2[4];
#pragma unroll
    for (int ct = 0; ct < 4; ++ct) acc2[ct] = (f32x4){0.f, 0.f, 0.f, 0.f};
#pragma unroll
    for (int kt = 0; kt < 2; ++kt) {
      U16x8 a;
      if (lr < 8) a.u = ((const uint4*)o1[lr])[kt * 4 + lg];
      else a.u = make_uint4(0, 0, 0, 0);
#pragma unroll
      for (int ct = 0; ct < 4; ++ct) {
        U16x8 b;
        b.u = *(const uint4*)&w2f[(((ct << 1) | kt) * 64 + t) * 8];
        acc2[ct] = __builtin_amdgcn_mfma_f32_16x16x32_bf16(a.s, b.s, acc2[ct], 0, 0, 0);
      }
    }
    float asw2_t[4], adw2_t[4];
#pragma unroll
    for (int ct = 0; ct < 4; ++ct) {
      asw2_t[ct] = as2w_g[ct * 16 + lr];
      adw2_t[ct] = ad2w_g[ct * 16 + lr];
    }
    const int gbase = blockIdx.x * 8;
#pragma unroll
    for (int reg = 0; reg < 4; ++reg) {
      int row = lg * 4 + reg;          // 0..15; rows 8-15 are padding
      bool ok = row < 8;
      int grow = gbase + row;
      float s0 = 0.f, d0 = 0.f;
#pragma unroll
      for (int ct = 0; ct < 4; ++ct) {
        float v = acc2[ct][reg];
        if (ok) h2b[(long long)grow * 64 + ct * 16 + lr] = bf16_1(v);
        s0 += v * asw2_t[ct]; d0 += v * adw2_t[ct];
      }
#pragma unroll
      for (int off = 1; off < 16; off <<= 1) {
        s0 += __shfl_xor(s0, off); d0 += __shfl_xor(d0, off);
      }
      if (ok && lr == 0) { as2[grow] = s0; ad2[grow] = d0; }
    }
  }
}

// ================= layer 2 fused GAT + classifier + log_softmax =================
__global__ __launch_bounds__(256) void k_gat2(
    const int* __restrict__ rowptr, const unsigned short* __restrict__ csr16,
    const unsigned* __restrict__ h2u, const float* __restrict__ as2,
    const float* __restrict__ ad2, const float* __restrict__ b2,
    const float* __restrict__ Wc, const float* __restrict__ bc,
    float* __restrict__ out) {
  __shared__ float2 sw[4][64];
  const int t = threadIdx.x;
  const int wv = t >> 6;
  const int n = blockIdx.x * 4 + wv;
  if (n >= NN) return;
  const int p = t & 63;
  const int half = p >> 5;
  const int q = p & 31;
  const int beg = rowptr[n], end = rowptr[n + 1];
  const int deg = end - beg;
  const float adn = ad2[n];

  float acc0 = 0.f, acc1 = 0.f;
  float inv;

  if (deg <= 64) {
    int s = 0; float e = -1e30f;
    if (p < deg) {
      s = csr16[beg + p];
      e = as2[s] + adn;
      e = fmaxf(e, 0.2f * e);
    }
    float m = e;
#pragma unroll
    for (int off = 1; off < 64; off <<= 1) m = fmaxf(m, __shfl_xor(m, off));
    float w = (p < deg) ? __expf(e - m) : 0.f;
    float d = w;
#pragma unroll
    for (int off = 1; off < 64; off <<= 1) d += __shfl_xor(d, off);
    sw[wv][p] = make_float2(__int_as_float(s), w);
    __builtin_amdgcn_wave_barrier();
    inv = 1.f / (d + 1e-16f);

    int niter = (deg + 1) >> 1;
    int i = 0;
    for (; i + 4 <= niter; i += 4) {
      float2 a[4]; unsigned v[4];
#pragma unroll
      for (int u = 0; u < 4; ++u) a[u] = sw[wv][2 * (i + u) + half];
#pragma unroll
      for (int u = 0; u < 4; ++u) v[u] = h2u[(__float_as_int(a[u].x) << 5) + q];
#pragma unroll
      for (int u = 0; u < 4; ++u) {
        acc0 += a[u].y * blo(v[u]);
        acc1 += a[u].y * bhi(v[u]);
      }
    }
    if (i + 2 <= niter) {
      float2 a0 = sw[wv][2 * i + half];
      float2 a1 = sw[wv][2 * (i + 1) + half];
      unsigned v0 = h2u[(__float_as_int(a0.x) << 5) + q];
      unsigned v1 = h2u[(__float_as_int(a1.x) << 5) + q];
      acc0 += a0.y * blo(v0); acc1 += a0.y * bhi(v0);
      acc0 += a1.y * blo(v1); acc1 += a1.y * bhi(v1);
      i += 2;
    }
    if (i < niter) {
      float2 a = sw[wv][2 * i + half];
      unsigned v = h2u[(__float_as_int(a.x) << 5) + q];
      acc0 += a.y * blo(v); acc1 += a.y * bhi(v);
    }
  } else {
    float m = -1e30f, d = 0.f;
    for (int k = beg + p; k < end; k += 64) {
      float e = as2[csr16[k]] + adn;
      e = fmaxf(e, 0.2f * e);
      if (e > m) { d *= __expf(m - e); m = e; }
      d += __expf(e - m);
    }
#pragma unroll
    for (int off = 1; off < 64; off <<= 1) {
      float mo = __shfl_xor(m, off), dd = __shfl_xor(d, off);
      float mn = fmaxf(m, mo);
      d = d * __expf(m - mn) + dd * __expf(mo - mn);
      m = mn;
    }
    inv = 1.f / (d + 1e-16f);
    for (int c0 = beg; c0 < end; c0 += 64) {
      int nc = end - c0; if (nc > 64) nc = 64;
      int s = 0; float w = 0.f;
      if (p < nc) {
        s = csr16[c0 + p];
        float e = as2[s] + adn;
        e = fmaxf(e, 0.2f * e);
        w = __expf(e - m);
      }
      __builtin_amdgcn_wave_barrier();
      sw[wv][p] = make_float2(__int_as_float(s), w);
      __builtin_amdgcn_wave_barrier();
      int niter = (nc + 1) >> 1;
      for (int i = 0; i < niter; ++i) {
        int j = 2 * i + half;
        float2 a = sw[wv][j < nc ? j : 0];
        float wj = (j < nc) ? a.y : 0.f;
        unsigned v = h2u[(__float_as_int(a.x) << 5) + q];
        acc0 += wj * blo(v); acc1 += wj * bhi(v);
      }
      __builtin_amdgcn_wave_barrier();
    }
  }

  acc0 += __shfl_xor(acc0, 32);
  acc1 += __shfl_xor(acc1, 32);
  float v0 = acc0 * inv + b2[2 * q];
  float v1 = acc1 * inv + b2[2 * q + 1];
  v0 = v0 > 0.f ? v0 : expm1f(v0);
  v1 = v1 > 0.f ? v1 : expm1f(v1);
  float l0 = v0 * Wc[4 * q] + v1 * Wc[4 * q + 2];
  float l1 = v0 * Wc[4 * q + 1] + v1 * Wc[4 * q + 3];
#pragma unroll
  for (int off = 1; off < 32; off <<= 1) {
    l0 += __shfl_xor(l0, off);
    l1 += __shfl_xor(l1, off);
  }
  if (p == 0) {
    l0 += bc[0]; l1 += bc[1];
    float mx = fmaxf(l0, l1);
    float lse = mx + logf(expf(l0 - mx) + expf(l1 - mx));
    out[n * 2] = l0 - lse;
    out[n * 2 + 1] = l1 - lse;
  }
}

extern "C" void kernel_launch(void* const* d_in, const int* in_sizes, int n_in,
                              void* d_out, int out_size, void* d_ws, size_t ws_size,
                              hipStream_t stream) {
  const float* x    = (const float*)d_in[0];
  const int*   ei   = (const int*)d_in[1];
  const float* W1   = (const float*)d_in[2];
  const float* as1w = (const float*)d_in[3];
  const float* ad1w = (const float*)d_in[4];
  const float* b1   = (const float*)d_in[5];
  const float* W2   = (const float*)d_in[6];
  const float* as2w = (const float*)d_in[7];
  const float* ad2w = (const float*)d_in[8];
  const float* b2   = (const float*)d_in[9];
  const float* Wc   = (const float*)d_in[10];
  const float* bc   = (const float*)d_in[11];
  float* out = (float*)d_out;

  const int* src = ei;
  const int* dst = ei + NE;

  // ---- workspace layout ----
  char* p = (char*)d_ws;
  unsigned short* h1b = (unsigned short*)p; p += sizeof(unsigned short) * (long long)NN * 128;
  unsigned short* h2b = (unsigned short*)p; p += sizeof(unsigned short) * (long long)NN * 64;
  float* as1  = (float*)p; p += sizeof(float) * NN * 2;
  float* ad1  = (float*)p; p += sizeof(float) * NN * 2;
  float* as2  = (float*)p; p += sizeof(float) * NN;
  float* ad2  = (float*)p; p += sizeof(float) * NN;
  int* rowptr  = (int*)p; p += sizeof(int) * (NN + 64);
  int* bcur    = (int*)p; p += sizeof(int) * ((NBUCK + 63) & ~63);
  unsigned* staging = (unsigned*)p; p += sizeof(unsigned) * (long long)NBUCK * CAP;
  unsigned short* csr16 = (unsigned short*)p; p += sizeof(unsigned short) * (long long)NT;
  unsigned short* w1f = (unsigned short*)p; p += sizeof(unsigned short) * 128 * 128;
  unsigned short* w2f = (unsigned short*)p; p += sizeof(unsigned short) * 64 * 64;

  // ---- prep -> fused(bucketF + gemm1) -> scatter(inline bscan, builds rowptr) ----
  k_prep<<<(128 * 128 + 64 * 64 + 255) / 256, 256, 0, stream>>>(W1, W2, w1f, w2f, bcur);
  k_gb<<<NBLK_B + NBLK_G, 256, 0, stream>>>(src, dst, bcur, staging,
                                            x, w1f, as1w, ad1w, h1b, as1, ad1);
  k_scatter2<<<NBUCK, 256, 0, stream>>>(staging, bcur, rowptr, csr16);

  // ---- layer 1 aggregation + fused layer 2 GEMM ----
  k_gat1<<<NN / 8, 256, 0, stream>>>(rowptr, csr16, (const uint2*)h1b,
                                     (const float2*)as1, (const float2*)ad1, b1,
                                     w2f, as2w, ad2w, h2b, as2, ad2);

  // ---- layer 2 aggregation ----
  k_gat2<<<(NN + 3) / 4, 256, 0, stream>>>(rowptr, csr16, (const unsigned*)h2b,
                                           as2, ad2, b2, Wc, bc, out);
}

// Round 18
// 114.837 us; speedup vs baseline: 1.0574x; 1.0574x over previous
//
#include <hip/hip_runtime.h>
#include <math.h>

#define NN 50000          // nodes
#define NE 800000         // edges (without self loops)
#define NT (NE + NN)      // edges incl self loops
#define NBUCK 196         // dst>>8 buckets (256 nodes each)
#define BE 4096           // edges per bucket block
#define NBLK_B ((NT + BE - 1) / BE)              // 208
#define CAP 6144          // static staging capacity per bucket (max ~4.6k)
#define NBLK_G ((NN + 63) / 64)                  // 782 gemm1 blocks

typedef short bf16x8 __attribute__((ext_vector_type(8)));
typedef float f32x4 __attribute__((ext_vector_type(4)));
union U16x8 { uint4 u; bf16x8 s; };

__device__ __forceinline__ unsigned pk_bf16x2(float x, float y) {
  unsigned ux = __float_as_uint(x); ux = ux + 0x7FFFu + ((ux >> 16) & 1u);
  unsigned uy = __float_as_uint(y); uy = uy + 0x7FFFu + ((uy >> 16) & 1u);
  return (ux >> 16) | (uy & 0xFFFF0000u);
}
__device__ __forceinline__ unsigned short bf16_1(float x) {
  unsigned u = __float_as_uint(x); u = u + 0x7FFFu + ((u >> 16) & 1u);
  return (unsigned short)(u >> 16);
}
__device__ __forceinline__ float blo(unsigned v) { return __uint_as_float(v << 16); }
__device__ __forceinline__ float bhi(unsigned v) { return __uint_as_float(v & 0xFFFF0000u); }

// ================= prep: weight frags + static bucket cursors =================
__global__ __launch_bounds__(256) void k_prep(const float* __restrict__ W1, const float* __restrict__ W2,
                                              unsigned short* __restrict__ w1f,
                                              unsigned short* __restrict__ w2f,
                                              int* __restrict__ bcur) {
  int i = blockIdx.x * 256 + threadIdx.x;
  if (i < NBUCK) bcur[i] = i * CAP;
  if (i < 128 * 128) {
    int k = i >> 7, col = i & 127;
    int ct = col >> 4, kt = k >> 5, lane = (((k >> 3) & 3) << 4) | (col & 15), j = k & 7;
    w1f[(((ct << 2) | kt) * 64 + lane) * 8 + j] = bf16_1(W1[i]);
  } else if (i < 128 * 128 + 64 * 64) {
    int e = i - 128 * 128;
    int k = e >> 6, col = e & 63;
    int ct = col >> 4, kt = k >> 5, lane = (((k >> 3) & 3) << 4) | (col & 15), j = k & 7;
    w2f[(((ct << 1) | kt) * 64 + lane) * 8 + j] = bf16_1(W2[e]);
  }
}

// ================= fused hetero kernel: bucketF (blocks 0..NBLK_B) + gemm1 (rest) =================
__global__ __launch_bounds__(256) void k_gb(
    const int* __restrict__ src, const int* __restrict__ dst,
    int* __restrict__ bcur, unsigned* __restrict__ staging,
    const float* __restrict__ x, const unsigned short* __restrict__ w1f,
    const float* __restrict__ asw_g, const float* __restrict__ adw_g,
    unsigned short* __restrict__ h1b, float* __restrict__ as1, float* __restrict__ ad1) {
  __shared__ int hist[NBUCK];
  __shared__ int base[NBUCK];
  if (blockIdx.x < NBLK_B) {
    const int t = threadIdx.x;
    const int e0 = blockIdx.x * BE;
    if (t < NBUCK) hist[t] = 0;
    __syncthreads();
    for (int j = t; j < BE; j += 256) {
      int i = e0 + j;
      if (i >= NT) break;
      int d = (i < NE) ? dst[i] : (i - NE);
      atomicAdd(&hist[d >> 8], 1);
    }
    __syncthreads();
    if (t < NBUCK) {
      int c = hist[t];
      base[t] = c ? atomicAdd(&bcur[t], c) : 0;
      hist[t] = 0;
    }
    __syncthreads();
    for (int j = t; j < BE; j += 256) {
      int i = e0 + j;
      if (i >= NT) break;
      int s, d;
      if (i < NE) { s = src[i]; d = dst[i]; } else { s = d = i - NE; }
      int b = d >> 8;
      int off = atomicAdd(&hist[b], 1);
      staging[base[b] + off] = ((unsigned)d << 16) | (unsigned)s;
    }
    return;
  }
  // ---- gemm1 ----
  const int bid = blockIdx.x - NBLK_B;
  const int t = threadIdx.x;
  const int wid = t >> 6, l = t & 63;
  const int lr = l & 15, lg = l >> 4;
  const int arow = bid * 64 + wid * 16 + lr;
  const bool aok = arow < NN;

  float asw_t[8], adw_t[8];
#pragma unroll
  for (int ct = 0; ct < 8; ++ct) {
    asw_t[ct] = asw_g[ct * 16 + lr];
    adw_t[ct] = adw_g[ct * 16 + lr];
  }

  f32x4 acc[8];
#pragma unroll
  for (int ct = 0; ct < 8; ++ct) acc[ct] = (f32x4){0.f, 0.f, 0.f, 0.f};

#pragma unroll
  for (int kt = 0; kt < 4; ++kt) {
    U16x8 a;
    if (aok) {
      const float* xp = &x[(long long)arow * 128 + kt * 32 + lg * 8];
      float4 f0 = *(const float4*)xp;
      float4 f1 = *(const float4*)(xp + 4);
      a.u.x = pk_bf16x2(f0.x, f0.y); a.u.y = pk_bf16x2(f0.z, f0.w);
      a.u.z = pk_bf16x2(f1.x, f1.y); a.u.w = pk_bf16x2(f1.z, f1.w);
    } else {
      a.u = make_uint4(0, 0, 0, 0);
    }
#pragma unroll
    for (int ct = 0; ct < 8; ++ct) {
      U16x8 b;
      b.u = *(const uint4*)&w1f[(((ct << 2) | kt) * 64 + l) * 8];
      acc[ct] = __builtin_amdgcn_mfma_f32_16x16x32_bf16(a.s, b.s, acc[ct], 0, 0, 0);
    }
  }

  const int gr0 = bid * 64 + wid * 16 + lg * 4;
#pragma unroll
  for (int reg = 0; reg < 4; ++reg) {
    int grow = gr0 + reg;
    bool ok = grow < NN;
    float s0 = 0.f, s1 = 0.f, d0 = 0.f, d1 = 0.f;
#pragma unroll
    for (int ct = 0; ct < 8; ++ct) {
      float v = acc[ct][reg];
      if (ok) h1b[(long long)grow * 128 + ct * 16 + lr] = bf16_1(v);
      if (ct < 4) { s0 += v * asw_t[ct]; d0 += v * adw_t[ct]; }
      else        { s1 += v * asw_t[ct]; d1 += v * adw_t[ct]; }
    }
#pragma unroll
    for (int off = 1; off < 16; off <<= 1) {
      s0 += __shfl_xor(s0, off); d0 += __shfl_xor(d0, off);
      s1 += __shfl_xor(s1, off); d1 += __shfl_xor(d1, off);
    }
    if (ok && lr == 0) {
      as1[grow * 2] = s0; as1[grow * 2 + 1] = s1;
      ad1[grow * 2] = d0; ad1[grow * 2 + 1] = d1;
    }
  }
}

// ================= per-bucket: inline bucket-scan + build rowptr + scatter =================
__global__ __launch_bounds__(256) void k_scatter2(const unsigned* __restrict__ staging,
                                                  const int* __restrict__ bcur,
                                                  int* __restrict__ rowptr,
                                                  unsigned short* __restrict__ csr16) {
  __shared__ int lcnt[256];
  __shared__ int wsum[4];
  __shared__ int sOff, sTot;
  const int b = blockIdx.x;
  const int t = threadIdx.x;
  const int nlo = b << 8;
  const int l = t & 63, w = t >> 6;

  int bc = (t < NBUCK) ? bcur[t] - t * CAP : 0;
  int sc = bc;
#pragma unroll
  for (int off = 1; off < 64; off <<= 1) {
    int u = __shfl_up(sc, off);
    if (l >= off) sc += u;
  }
  if (l == 63) wsum[w] = sc;
  __syncthreads();
  {
    int wo = 0;
    for (int i = 0; i < w; ++i) wo += wsum[i];
    int incl = sc + wo;
    if (t == b) sOff = incl - bc;
    if (t == 255) sTot = incl;
  }
  lcnt[t] = 0;
  __syncthreads();

  const int s0 = b * CAP;
  const int cnt = bcur[b] - s0;
  for (int k = t; k < cnt; k += 256)
    atomicAdd(&lcnt[(int)(staging[s0 + k] >> 16) - nlo], 1);
  __syncthreads();
  int v = lcnt[t];
  int sc2 = v;
#pragma unroll
  for (int off = 1; off < 64; off <<= 1) {
    int u = __shfl_up(sc2, off);
    if (l >= off) sc2 += u;
  }
  __syncthreads();
  if (l == 63) wsum[w] = sc2;
  __syncthreads();
  int wo = 0;
  for (int i = 0; i < w; ++i) wo += wsum[i];
  const int base = sOff + sc2 + wo - v;
  if (nlo + t < NN) rowptr[nlo + t] = base;
  if (b == NBUCK - 1 && t == 0) rowptr[NN] = sTot;
  __syncthreads();
  lcnt[t] = base;
  __syncthreads();
  for (int k = t; k < cnt; k += 256) {
    unsigned e = staging[s0 + k];
    int d = (int)(e >> 16) - nlo;
    int pos = atomicAdd(&lcnt[d], 1);
    csr16[pos] = (unsigned short)(e & 0xFFFFu);
  }
}

// ================= layer 1 fused GAT (wave-per-node, 8 gathers in flight) =================
__global__ __launch_bounds__(256) void k_gat1(
    const int* __restrict__ rowptr, const unsigned short* __restrict__ csr16,
    const unsigned* __restrict__ h1u, const float2* __restrict__ as1,
    const float2* __restrict__ ad1, const float* __restrict__ b1,
    unsigned* __restrict__ out1b) {
  __shared__ float2 sw[4][2][64];
  const int t = threadIdx.x;
  const int wv = t >> 6;
  const int n = blockIdx.x * 4 + wv;
  if (n >= NN) return;
  const int p = t & 63;
  const int h = p >> 5;
  const int beg = rowptr[n], end = rowptr[n + 1];
  const int deg = end - beg;
  const float2 adn = ad1[n];

  float acc0 = 0.f, acc1 = 0.f;
  float inv;

  if (deg <= 64) {
    int s = 0; float e0 = -1e30f, e1 = -1e30f;
    if (p < deg) {
      s = csr16[beg + p];
      float2 a = as1[s];
      e0 = a.x + adn.x; e0 = fmaxf(e0, 0.2f * e0);
      e1 = a.y + adn.y; e1 = fmaxf(e1, 0.2f * e1);
    }
    float m0 = e0, m1 = e1;
#pragma unroll
    for (int off = 1; off < 64; off <<= 1) {
      m0 = fmaxf(m0, __shfl_xor(m0, off));
      m1 = fmaxf(m1, __shfl_xor(m1, off));
    }
    float w0 = (p < deg) ? __expf(e0 - m0) : 0.f;
    float w1 = (p < deg) ? __expf(e1 - m1) : 0.f;
    float d0 = w0, d1 = w1;
#pragma unroll
    for (int off = 1; off < 64; off <<= 1) {
      d0 += __shfl_xor(d0, off);
      d1 += __shfl_xor(d1, off);
    }
    sw[wv][0][p] = make_float2(__int_as_float(s), w0);
    sw[wv][1][p] = make_float2(__int_as_float(s), w1);
    __builtin_amdgcn_wave_barrier();
    inv = 1.f / ((h ? d1 : d0) + 1e-16f);

    int j = 0;
    for (; j + 8 <= deg; j += 8) {
      float2 a[8]; unsigned v[8];
#pragma unroll
      for (int u = 0; u < 8; ++u) a[u] = sw[wv][h][j + u];
#pragma unroll
      for (int u = 0; u < 8; ++u) v[u] = h1u[(__float_as_int(a[u].x) << 6) + p];
#pragma unroll
      for (int u = 0; u < 8; ++u) {
        acc0 += a[u].y * blo(v[u]);
        acc1 += a[u].y * bhi(v[u]);
      }
    }
    if (j + 4 <= deg) {
      float2 a[4]; unsigned v[4];
#pragma unroll
      for (int u = 0; u < 4; ++u) a[u] = sw[wv][h][j + u];
#pragma unroll
      for (int u = 0; u < 4; ++u) v[u] = h1u[(__float_as_int(a[u].x) << 6) + p];
#pragma unroll
      for (int u = 0; u < 4; ++u) {
        acc0 += a[u].y * blo(v[u]);
        acc1 += a[u].y * bhi(v[u]);
      }
      j += 4;
    }
    for (; j < deg; ++j) {
      float2 a = sw[wv][h][j];
      unsigned v = h1u[(__float_as_int(a.x) << 6) + p];
      acc0 += a.y * blo(v); acc1 += a.y * bhi(v);
    }
  } else {
    float m0 = -1e30f, d0 = 0.f, m1 = -1e30f, d1 = 0.f;
    for (int k = beg + p; k < end; k += 64) {
      float2 a = as1[csr16[k]];
      float e0 = a.x + adn.x; e0 = fmaxf(e0, 0.2f * e0);
      float e1 = a.y + adn.y; e1 = fmaxf(e1, 0.2f * e1);
      if (e0 > m0) { d0 *= __expf(m0 - e0); m0 = e0; }
      d0 += __expf(e0 - m0);
      if (e1 > m1) { d1 *= __expf(m1 - e1); m1 = e1; }
      d1 += __expf(e1 - m1);
    }
#pragma unroll
    for (int off = 1; off < 64; off <<= 1) {
      float mo = __shfl_xor(m0, off), dd = __shfl_xor(d0, off);
      float mn = fmaxf(m0, mo);
      d0 = d0 * __expf(m0 - mn) + dd * __expf(mo - mn);
      m0 = mn;
      mo = __shfl_xor(m1, off); dd = __shfl_xor(d1, off);
      mn = fmaxf(m1, mo);
      d1 = d1 * __expf(m1 - mn) + dd * __expf(mo - mn);
      m1 = mn;
    }
    inv = 1.f / ((h ? d1 : d0) + 1e-16f);
    for (int c0 = beg; c0 < end; c0 += 64) {
      int nc = end - c0; if (nc > 64) nc = 64;
      int s = 0; float w0 = 0.f, w1 = 0.f;
      if (p < nc) {
        s = csr16[c0 + p];
        float2 a = as1[s];
        float e0 = a.x + adn.x; e0 = fmaxf(e0, 0.2f * e0);
        float e1 = a.y + adn.y; e1 = fmaxf(e1, 0.2f * e1);
        w0 = __expf(e0 - m0);
        w1 = __expf(e1 - m1);
      }
      __builtin_amdgcn_wave_barrier();
      sw[wv][0][p] = make_float2(__int_as_float(s), w0);
      sw[wv][1][p] = make_float2(__int_as_float(s), w1);
      __builtin_amdgcn_wave_barrier();
      for (int j = 0; j < nc; ++j) {
        float2 a = sw[wv][h][j];
        unsigned v = h1u[(__float_as_int(a.x) << 6) + p];
        acc0 += a.y * blo(v); acc1 += a.y * bhi(v);
      }
      __builtin_amdgcn_wave_barrier();
    }
  }

  acc0 *= inv; acc1 *= inv;
  acc0 += __shfl_xor(acc0, 32);
  acc1 += __shfl_xor(acc1, 32);
  if (p < 32) {
    float u0 = 0.5f * acc0 + b1[2 * p];
    float u1 = 0.5f * acc1 + b1[2 * p + 1];
    u0 = u0 > 0.f ? u0 : expm1f(u0);
    u1 = u1 > 0.f ? u1 : expm1f(u1);
    out1b[n * 32 + p] = pk_bf16x2(u0, u1);
  }
}

// ================= layer 2 MFMA GEMM =================
__global__ __launch_bounds__(256) void k_gemm2(
    const unsigned short* __restrict__ in_b, const unsigned short* __restrict__ w2f,
    const float* __restrict__ asw_g, const float* __restrict__ adw_g,
    unsigned short* __restrict__ h2b, float* __restrict__ as2, float* __restrict__ ad2) {
  const int t = threadIdx.x;
  const int wid = t >> 6, l = t & 63;
  const int lr = l & 15, lg = l >> 4;
  const int arow = blockIdx.x * 64 + wid * 16 + lr;
  const bool aok = arow < NN;

  float asw_t[4], adw_t[4];
#pragma unroll
  for (int ct = 0; ct < 4; ++ct) {
    asw_t[ct] = asw_g[ct * 16 + lr];
    adw_t[ct] = adw_g[ct * 16 + lr];
  }

  f32x4 acc[4];
#pragma unroll
  for (int ct = 0; ct < 4; ++ct) acc[ct] = (f32x4){0.f, 0.f, 0.f, 0.f};

#pragma unroll
  for (int kt = 0; kt < 2; ++kt) {
    U16x8 a;
    if (aok) a.u = *(const uint4*)&in_b[(long long)arow * 64 + kt * 32 + lg * 8];
    else a.u = make_uint4(0, 0, 0, 0);
#pragma unroll
    for (int ct = 0; ct < 4; ++ct) {
      U16x8 b;
      b.u = *(const uint4*)&w2f[(((ct << 1) | kt) * 64 + l) * 8];
      acc[ct] = __builtin_amdgcn_mfma_f32_16x16x32_bf16(a.s, b.s, acc[ct], 0, 0, 0);
    }
  }

  const int gr0 = blockIdx.x * 64 + wid * 16 + lg * 4;
#pragma unroll
  for (int reg = 0; reg < 4; ++reg) {
    int grow = gr0 + reg;
    bool ok = grow < NN;
    float s0 = 0.f, d0 = 0.f;
#pragma unroll
    for (int ct = 0; ct < 4; ++ct) {
      float v = acc[ct][reg];
      if (ok) h2b[(long long)grow * 64 + ct * 16 + lr] = bf16_1(v);
      s0 += v * asw_t[ct]; d0 += v * adw_t[ct];
    }
#pragma unroll
    for (int off = 1; off < 16; off <<= 1) {
      s0 += __shfl_xor(s0, off); d0 += __shfl_xor(d0, off);
    }
    if (ok && lr == 0) { as2[grow] = s0; ad2[grow] = d0; }
  }
}

// ================= layer 2 fused GAT + classifier + log_softmax =================
__global__ __launch_bounds__(256) void k_gat2(
    const int* __restrict__ rowptr, const unsigned short* __restrict__ csr16,
    const unsigned* __restrict__ h2u, const float* __restrict__ as2,
    const float* __restrict__ ad2, const float* __restrict__ b2,
    const float* __restrict__ Wc, const float* __restrict__ bc,
    float* __restrict__ out) {
  __shared__ float2 sw[4][64];
  const int t = threadIdx.x;
  const int wv = t >> 6;
  const int n = blockIdx.x * 4 + wv;
  if (n >= NN) return;
  const int p = t & 63;
  const int half = p >> 5;
  const int q = p & 31;
  const int beg = rowptr[n], end = rowptr[n + 1];
  const int deg = end - beg;
  const float adn = ad2[n];

  float acc0 = 0.f, acc1 = 0.f;
  float inv;

  if (deg <= 64) {
    int s = 0; float e = -1e30f;
    if (p < deg) {
      s = csr16[beg + p];
      e = as2[s] + adn;
      e = fmaxf(e, 0.2f * e);
    }
    float m = e;
#pragma unroll
    for (int off = 1; off < 64; off <<= 1) m = fmaxf(m, __shfl_xor(m, off));
    float w = (p < deg) ? __expf(e - m) : 0.f;
    float d = w;
#pragma unroll
    for (int off = 1; off < 64; off <<= 1) d += __shfl_xor(d, off);
    sw[wv][p] = make_float2(__int_as_float(s), w);
    __builtin_amdgcn_wave_barrier();
    inv = 1.f / (d + 1e-16f);

    int niter = (deg + 1) >> 1;
    int i = 0;
    for (; i + 4 <= niter; i += 4) {
      float2 a[4]; unsigned v[4];
#pragma unroll
      for (int u = 0; u < 4; ++u) a[u] = sw[wv][2 * (i + u) + half];
#pragma unroll
      for (int u = 0; u < 4; ++u) v[u] = h2u[(__float_as_int(a[u].x) << 5) + q];
#pragma unroll
      for (int u = 0; u < 4; ++u) {
        acc0 += a[u].y * blo(v[u]);
        acc1 += a[u].y * bhi(v[u]);
      }
    }
    if (i + 2 <= niter) {
      float2 a0 = sw[wv][2 * i + half];
      float2 a1 = sw[wv][2 * (i + 1) + half];
      unsigned v0 = h2u[(__float_as_int(a0.x) << 5) + q];
      unsigned v1 = h2u[(__float_as_int(a1.x) << 5) + q];
      acc0 += a0.y * blo(v0); acc1 += a0.y * bhi(v0);
      acc0 += a1.y * blo(v1); acc1 += a1.y * bhi(v1);
      i += 2;
    }
    if (i < niter) {
      float2 a = sw[wv][2 * i + half];
      unsigned v = h2u[(__float_as_int(a.x) << 5) + q];
      acc0 += a.y * blo(v); acc1 += a.y * bhi(v);
    }
  } else {
    float m = -1e30f, d = 0.f;
    for (int k = beg + p; k < end; k += 64) {
      float e = as2[csr16[k]] + adn;
      e = fmaxf(e, 0.2f * e);
      if (e > m) { d *= __expf(m - e); m = e; }
      d += __expf(e - m);
    }
#pragma unroll
    for (int off = 1; off < 64; off <<= 1) {
      float mo = __shfl_xor(m, off), dd = __shfl_xor(d, off);
      float mn = fmaxf(m, mo);
      d = d * __expf(m - mn) + dd * __expf(mo - mn);
      m = mn;
    }
    inv = 1.f / (d + 1e-16f);
    for (int c0 = beg; c0 < end; c0 += 64) {
      int nc = end - c0; if (nc > 64) nc = 64;
      int s = 0; float w = 0.f;
      if (p < nc) {
        s = csr16[c0 + p];
        float e = as2[s] + adn;
        e = fmaxf(e, 0.2f * e);
        w = __expf(e - m);
      }
      __builtin_amdgcn_wave_barrier();
      sw[wv][p] = make_float2(__int_as_float(s), w);
      __builtin_amdgcn_wave_barrier();
      int niter = (nc + 1) >> 1;
      for (int i = 0; i < niter; ++i) {
        int j = 2 * i + half;
        float2 a = sw[wv][j < nc ? j : 0];
        float wj = (j < nc) ? a.y : 0.f;
        unsigned v = h2u[(__float_as_int(a.x) << 5) + q];
        acc0 += wj * blo(v); acc1 += wj * bhi(v);
      }
      __builtin_amdgcn_wave_barrier();
    }
  }

  acc0 += __shfl_xor(acc0, 32);
  acc1 += __shfl_xor(acc1, 32);
  float v0 = acc0 * inv + b2[2 * q];
  float v1 = acc1 * inv + b2[2 * q + 1];
  v0 = v0 > 0.f ? v0 : expm1f(v0);
  v1 = v1 > 0.f ? v1 : expm1f(v1);
  float l0 = v0 * Wc[4 * q] + v1 * Wc[4 * q + 2];
  float l1 = v0 * Wc[4 * q + 1] + v1 * Wc[4 * q + 3];
#pragma unroll
  for (int off = 1; off < 32; off <<= 1) {
    l0 += __shfl_xor(l0, off);
    l1 += __shfl_xor(l1, off);
  }
  if (p == 0) {
    l0 += bc[0]; l1 += bc[1];
    float mx = fmaxf(l0, l1);
    float lse = mx + logf(expf(l0 - mx) + expf(l1 - mx));
    out[n * 2] = l0 - lse;
    out[n * 2 + 1] = l1 - lse;
  }
}

extern "C" void kernel_launch(void* const* d_in, const int* in_sizes, int n_in,
                              void* d_out, int out_size, void* d_ws, size_t ws_size,
                              hipStream_t stream) {
  const float* x    = (const float*)d_in[0];
  const int*   ei   = (const int*)d_in[1];
  const float* W1   = (const float*)d_in[2];
  const float* as1w = (const float*)d_in[3];
  const float* ad1w = (const float*)d_in[4];
  const float* b1   = (const float*)d_in[5];
  const float* W2   = (const float*)d_in[6];
  const float* as2w = (const float*)d_in[7];
  const float* ad2w = (const float*)d_in[8];
  const float* b2   = (const float*)d_in[9];
  const float* Wc   = (const float*)d_in[10];
  const float* bc   = (const float*)d_in[11];
  float* out = (float*)d_out;

  const int* src = ei;
  const int* dst = ei + NE;

  // ---- workspace layout ----
  char* p = (char*)d_ws;
  unsigned short* h1b = (unsigned short*)p; p += sizeof(unsigned short) * (long long)NN * 128;
  unsigned short* out1b = (unsigned short*)p; p += sizeof(unsigned short) * (long long)NN * 64;
  unsigned short* h2b = (unsigned short*)p; p += sizeof(unsigned short) * (long long)NN * 64;
  float* as1  = (float*)p; p += sizeof(float) * NN * 2;
  float* ad1  = (float*)p; p += sizeof(float) * NN * 2;
  float* as2  = (float*)p; p += sizeof(float) * NN;
  float* ad2  = (float*)p; p += sizeof(float) * NN;
  int* rowptr  = (int*)p; p += sizeof(int) * (NN + 64);
  int* bcur    = (int*)p; p += sizeof(int) * ((NBUCK + 63) & ~63);
  unsigned* staging = (unsigned*)p; p += sizeof(unsigned) * (long long)NBUCK * CAP;
  unsigned short* csr16 = (unsigned short*)p; p += sizeof(unsigned short) * (long long)NT;
  unsigned short* w1f = (unsigned short*)p; p += sizeof(unsigned short) * 128 * 128;
  unsigned short* w2f = (unsigned short*)p; p += sizeof(unsigned short) * 64 * 64;

  // ---- prep -> fused(bucketF + gemm1) -> scatter(inline bscan, builds rowptr) ----
  k_prep<<<(128 * 128 + 64 * 64 + 255) / 256, 256, 0, stream>>>(W1, W2, w1f, w2f, bcur);
  k_gb<<<NBLK_B + NBLK_G, 256, 0, stream>>>(src, dst, bcur, staging,
                                            x, w1f, as1w, ad1w, h1b, as1, ad1);
  k_scatter2<<<NBUCK, 256, 0, stream>>>(staging, bcur, rowptr, csr16);

  // ---- layer 1 aggregation ----
  k_gat1<<<(NN + 3) / 4, 256, 0, stream>>>(rowptr, csr16, (const unsigned*)h1b,
                                           (const float2*)as1, (const float2*)ad1, b1,
                                           (unsigned*)out1b);

  // ---- layer 2 ----
  k_gemm2<<<(NN + 63) / 64, 256, 0, stream>>>(out1b, w2f, as2w, ad2w, h2b, as2, ad2);
  k_gat2<<<(NN + 3) / 4, 256, 0, stream>>>(rowptr, csr16, (const unsigned*)h2b,
                                           as2, ad2, b2, Wc, bc, out);
}